// Round 4
// baseline (258.700 us; speedup 1.0000x reference)
//
#include <hip/hip_runtime.h>
#include <hip/hip_bf16.h>

#define D_MODEL 1024
#define NH 16
#define HD 64
#define BATCH 2
#define SEQ 2048
#define M_TOTAL (BATCH*SEQ)   // 4096

typedef _Float16 f16;
typedef _Float16 half8 __attribute__((ext_vector_type(8)));
typedef _Float16 half4v __attribute__((ext_vector_type(4)));
typedef float floatx4 __attribute__((ext_vector_type(4)));

__device__ inline void gload_lds16(const void* g, void* l) {
    __builtin_amdgcn_global_load_lds(
        (const __attribute__((address_space(1))) unsigned int*)g,
        (__attribute__((address_space(3))) unsigned int*)l, 16, 0, 0);
}

// ---------------- fp32 -> fp16 cast ----------------
__global__ void cvt_f32_f16(const float* __restrict__ src, f16* __restrict__ dst, int n4) {
    int i = blockIdx.x * blockDim.x + threadIdx.x;
    if (i < n4) {
        float4 v = ((const float4*)src)[i];
        half4v o = { (f16)v.x, (f16)v.y, (f16)v.z, (f16)v.w };
        *(half4v*)(dst + (long)i * 4) = o;
    }
}

// ---------------- fp32 [R][C] -> fp16 [C][R] transpose-cast ----------------
__global__ void transpose_cvt(const float* __restrict__ src, f16* __restrict__ dst, int R, int C) {
    __shared__ float tile[32][33];
    int tx = threadIdx.x;
    int ty = threadIdx.y;
    int c0 = blockIdx.x * 32;
    int r0 = blockIdx.y * 32;
    for (int yy = 0; yy < 32; yy += 8)
        tile[ty + yy][tx] = src[(long)(r0 + ty + yy) * C + c0 + tx];
    __syncthreads();
    for (int yy = 0; yy < 32; yy += 8)
        dst[(long)(c0 + ty + yy) * R + r0 + tx] = (f16)tile[tx][ty + yy];
}

// ---------------- 128xTN-tile fp16 MFMA GEMM, BK=64, XOR-swizzled LDS ----------------
// MODE 0 (TN=128): scatter -> Qh [bh][s][d] (x0.125), Kh [bh][s][d], Vtg [bh][d][s]
// MODE 1 (TN=64):  out[m][n] = acc + bias (fp32)
template<int MODE, int TN>
__global__ __launch_bounds__(256) void gemm_mfma(
    const f16* __restrict__ A, const f16* __restrict__ BT,
    const float* __restrict__ bias,
    f16* __restrict__ Qh, f16* __restrict__ Kh, f16* __restrict__ Vtg,
    float* __restrict__ out, int Kdim)
{
    constexpr int NF = TN / 32;
    __shared__ f16 Ah[128 * 64];
    __shared__ f16 Bh[TN * 64];
    int tid  = threadIdx.x;
    int wid  = tid >> 6;
    int lane = tid & 63;
    int quad = lane >> 4;
    int l16  = lane & 15;
    int m0 = blockIdx.y * 128;
    int n0 = blockIdx.x * TN;
    int mrow = (wid >> 1) * 64;
    int ncol = (wid & 1) * (TN / 2);
    int grow = lane >> 3;
    int gchunk = (lane & 7) ^ (grow & 7);
    int sw0 = ((quad)     ^ (l16 & 7)) * 8;
    int sw1 = ((quad + 4) ^ (l16 & 7)) * 8;

    floatx4 acc[4][NF];
    #pragma unroll
    for (int mb = 0; mb < 4; mb++)
        #pragma unroll
        for (int nb = 0; nb < NF; nb++) acc[mb][nb] = (floatx4){0.f, 0.f, 0.f, 0.f};

    const f16* Abase = A + (long)m0 * Kdim;
    const f16* Bbase = BT + (long)n0 * Kdim;

    for (int k0 = 0; k0 < Kdim; k0 += 64) {
        #pragma unroll
        for (int j = 0; j < 4; j++) {
            int r = j * 32 + wid * 8 + grow;
            gload_lds16(Abase + (long)r * Kdim + k0 + gchunk * 8, &Ah[(j * 32 + wid * 8) * 64]);
        }
        #pragma unroll
        for (int j = 0; j < TN / 32; j++) {
            int r = j * 32 + wid * 8 + grow;
            gload_lds16(Bbase + (long)r * Kdim + k0 + gchunk * 8, &Bh[(j * 32 + wid * 8) * 64]);
        }
        __syncthreads();
        #pragma unroll
        for (int h = 0; h < 2; h++) {
            int sw = h ? sw1 : sw0;
            half8 af[4];
            #pragma unroll
            for (int mb = 0; mb < 4; mb++)
                af[mb] = *(const half8*)&Ah[(mrow + mb * 16 + l16) * 64 + sw];
            #pragma unroll
            for (int nb = 0; nb < NF; nb++) {
                half8 bf = *(const half8*)&Bh[(ncol + nb * 16 + l16) * 64 + sw];
                #pragma unroll
                for (int mb = 0; mb < 4; mb++)
                    acc[mb][nb] = __builtin_amdgcn_mfma_f32_16x16x32_f16(af[mb], bf, acc[mb][nb], 0, 0, 0);
            }
        }
        __syncthreads();
    }

    #pragma unroll
    for (int nb = 0; nb < NF; nb++) {
        int n = n0 + ncol + nb * 16 + l16;
        float bv = bias[n];
        int head = 0, t = 0, d = 0;
        if (MODE == 0) { head = n / 192; int rem = n % 192; t = rem / 64; d = rem % 64; }
        #pragma unroll
        for (int mb = 0; mb < 4; mb++) {
            int mbase = m0 + mrow + mb * 16 + quad * 4;
            if (MODE == 0) {
                int b = mbase >> 11;
                int s = mbase & 2047;
                long bh = b * NH + head;
                if (t == 2) {
                    half4v pack;
                    #pragma unroll
                    for (int r = 0; r < 4; r++) pack[r] = (f16)(acc[mb][nb][r] + bv);
                    *(half4v*)&Vtg[(bh * HD + d) * SEQ + s] = pack;
                } else if (t == 0) {
                    #pragma unroll
                    for (int r = 0; r < 4; r++)
                        Qh[(bh * SEQ + s + r) * HD + d] = (f16)((acc[mb][nb][r] + bv) * 0.125f);
                } else {
                    #pragma unroll
                    for (int r = 0; r < 4; r++)
                        Kh[(bh * SEQ + s + r) * HD + d] = (f16)(acc[mb][nb][r] + bv);
                }
            } else {
                #pragma unroll
                for (int r = 0; r < 4; r++)
                    out[(long)(mbase + r) * D_MODEL + n] = acc[mb][nb][r] + bv;
            }
        }
    }
}

// ---------------- flash attention v3 ----------------
// grid (SEQ/64, B*H), 128 threads (2 waves x 32 q-rows).
// S^T = K.Q^T via MFMA (acc initialized with mask float4 -> S = qk/8 + mask);
// p = expf(S) written as packed b64 into Pl; denominator via ones-column MFMA.
__global__ __launch_bounds__(128) void attn(
    const f16* __restrict__ Qh, const f16* __restrict__ Kh, const f16* __restrict__ Vtg,
    const float* __restrict__ mask, f16* __restrict__ valh)
{
    __shared__ f16 Kl[64 * 64];      // [key][d], swizzled 16B chunks
    __shared__ f16 Vt[64 * 64];      // [d][key], swizzled 16B chunks
    __shared__ f16 Pl[2][32 * 72];   // per-wave P [q][key], stride 72
    int tid  = threadIdx.x;
    int wid  = tid >> 6;             // 0..1
    int lane = tid & 63;
    int quad = lane >> 4;
    int l16  = lane & 15;
    int bh = blockIdx.y;
    int b  = bh >> 4;
    int h  = bh & 15;
    int q0 = blockIdx.x * 64 + wid * 32;

    int grow8 = lane >> 3;           // 0..7
    int gpos  = lane & 7;
    int sw0 = ((quad)     ^ (l16 & 7)) * 8;
    int sw1 = ((quad + 4) ^ (l16 & 7)) * 8;

    const f16* Qbase = Qh + ((long)bh * SEQ + q0) * HD;
    half8 qf[2][2];
    #pragma unroll
    for (int m = 0; m < 2; m++)
        #pragma unroll
        for (int c = 0; c < 2; c++)
            qf[m][c] = *(const half8*)&Qbase[(long)(m * 16 + l16) * HD + c * 32 + quad * 8];

    half8 vones;
    #pragma unroll
    for (int j = 0; j < 8; j++) vones[j] = (f16)1.0f;

    floatx4 Of[2][4];
    floatx4 Ofs[2];
    #pragma unroll
    for (int m = 0; m < 2; m++) {
        Ofs[m] = (floatx4){0.f, 0.f, 0.f, 0.f};
        #pragma unroll
        for (int nb = 0; nb < 4; nb++) Of[m][nb] = (floatx4){0.f, 0.f, 0.f, 0.f};
    }

    const f16* Kb = Kh + (long)bh * SEQ * HD;
    const f16* Vb = Vtg + (long)bh * HD * SEQ;

    for (int k0 = 0; k0 < SEQ; k0 += 64) {
        __syncthreads();   // previous-iter readers done before DMA overwrites
        #pragma unroll
        for (int j = 0; j < 4; j++) {
            int rb = j * 16 + wid * 8;
            int row = rb + grow8;
            int gk = gpos ^ (row & 7);
            gload_lds16(Kb + (long)(k0 + row) * HD + gk * 8, &Kl[rb * 64]);
            gload_lds16(Vb + (long)row * SEQ + k0 + gk * 8, &Vt[rb * 64]);
        }
        // prefetch mask tile as coalesced float4; completes at the barrier's vmcnt(0)
        float4 mk[2][4];
        #pragma unroll
        for (int m = 0; m < 2; m++)
            #pragma unroll
            for (int kb = 0; kb < 4; kb++)
                mk[m][kb] = *(const float4*)&mask[(long)(q0 + m * 16 + l16) * SEQ + k0 + kb * 16 + quad * 4];
        __syncthreads();

        #pragma unroll
        for (int kb = 0; kb < 4; kb++) {
            half8 kf0 = *(const half8*)&Kl[(kb * 16 + l16) * 64 + sw0];
            half8 kf1 = *(const half8*)&Kl[(kb * 16 + l16) * 64 + 32 + sw1 - 32];  // = sw1
            #pragma unroll
            for (int m = 0; m < 2; m++) {
                floatx4 s = (floatx4){mk[m][kb].x, mk[m][kb].y, mk[m][kb].z, mk[m][kb].w};
                s = __builtin_amdgcn_mfma_f32_16x16x32_f16(kf0, qf[m][0], s, 0, 0, 0);
                s = __builtin_amdgcn_mfma_f32_16x16x32_f16(kf1, qf[m][1], s, 0, 0, 0);
                // lane holds S[q=l16][key=kb*16+quad*4+r], r=0..3 contiguous keys
                half4v ph;
                #pragma unroll
                for (int r = 0; r < 4; r++) ph[r] = (f16)__expf(s[r]);
                *(half4v*)&Pl[wid][(m * 16 + l16) * 72 + kb * 16 + quad * 4] = ph;
            }
        }

        // wave-private LDS round-trip (C-layout -> A-layout); no barrier needed
        half8 pf[2][2];
        #pragma unroll
        for (int m = 0; m < 2; m++)
            #pragma unroll
            for (int c = 0; c < 2; c++)
                pf[m][c] = *(const half8*)&Pl[wid][(m * 16 + l16) * 72 + c * 32 + quad * 8];

        #pragma unroll
        for (int nb = 0; nb < 4; nb++) {
            half8 vf0 = *(const half8*)&Vt[(nb * 16 + l16) * 64 + sw0];
            half8 vf1 = *(const half8*)&Vt[(nb * 16 + l16) * 64 + sw1];
            #pragma unroll
            for (int m = 0; m < 2; m++) {
                Of[m][nb] = __builtin_amdgcn_mfma_f32_16x16x32_f16(pf[m][0], vf0, Of[m][nb], 0, 0, 0);
                Of[m][nb] = __builtin_amdgcn_mfma_f32_16x16x32_f16(pf[m][1], vf1, Of[m][nb], 0, 0, 0);
            }
        }
        #pragma unroll
        for (int m = 0; m < 2; m++) {
            Ofs[m] = __builtin_amdgcn_mfma_f32_16x16x32_f16(pf[m][0], vones, Ofs[m], 0, 0, 0);
            Ofs[m] = __builtin_amdgcn_mfma_f32_16x16x32_f16(pf[m][1], vones, Ofs[m], 0, 0, 0);
        }
    }

    #pragma unroll
    for (int m = 0; m < 2; m++) {
        floatx4 rs;
        #pragma unroll
        for (int r = 0; r < 4; r++) rs[r] = 1.f / Ofs[m][r];
        #pragma unroll
        for (int nb = 0; nb < 4; nb++)
            #pragma unroll
            for (int r = 0; r < 4; r++) {
                int q = q0 + m * 16 + quad * 4 + r;
                int d = nb * 16 + l16;
                valh[((long)(b * SEQ + q)) * D_MODEL + h * HD + d] = (f16)(Of[m][nb][r] * rs[r]);
            }
    }
}

extern "C" void kernel_launch(void* const* d_in, const int* in_sizes, int n_in,
                              void* d_out, int out_size, void* d_ws, size_t ws_size,
                              hipStream_t stream) {
    const float* x    = (const float*)d_in[0];
    const float* mask = (const float*)d_in[1];
    const float* Wqkv = (const float*)d_in[2];
    const float* bqkv = (const float*)d_in[3];
    const float* Wout = (const float*)d_in[4];
    const float* bout = (const float*)d_in[5];
    float* out = (float*)d_out;

    char* ws = (char*)d_ws;
    f16* xh    = (f16*)(ws + 0);          // 8 MB: [4096][1024]
    f16* WqkvT = (f16*)(ws + 8388608);    // 6 MB: [3072][1024]
    f16* WoutT = (f16*)(ws + 14680064);   // 2 MB: [1024][1024]
    f16* Qh    = (f16*)(ws + 16777216);   // 8 MB: [32][2048][64] (pre-scaled 1/8)
    f16* Kh    = (f16*)(ws + 25165824);   // 8 MB: [32][2048][64]
    f16* Vtg   = (f16*)(ws + 33554432);   // 8 MB: [32][64][2048] (V transposed)
    f16* valh  = (f16*)(ws + 41943040);   // 8 MB: [4096][1024]

    cvt_f32_f16<<<4096, 256, 0, stream>>>(x, xh, M_TOTAL * D_MODEL / 4);
    transpose_cvt<<<dim3(96, 32), dim3(32, 8), 0, stream>>>(Wqkv, WqkvT, 1024, 3072);
    transpose_cvt<<<dim3(32, 32), dim3(32, 8), 0, stream>>>(Wout, WoutT, 1024, 1024);
    gemm_mfma<0, 128><<<dim3(24, 32), 256, 0, stream>>>(xh, WqkvT, bqkv, Qh, Kh, Vtg, nullptr, 1024);
    attn<<<dim3(32, 32), 128, 0, stream>>>(Qh, Kh, Vtg, mask, valh);
    gemm_mfma<1, 64><<<dim3(16, 32), 256, 0, stream>>>(valh, WoutT, bout, nullptr, nullptr, nullptr, out, 1024);
}